// Round 1
// baseline (948.631 us; speedup 1.0000x reference)
//
#include <hip/hip_runtime.h>

#define T_STEPS 512
#define NTRAJ   4096
#define LAT     32
#define INPD    16
#define HID     20
#define CAT     48

__device__ __forceinline__ float fast_tanh(float x) {
    // tanh(x) = 1 - 2/(exp(2x)+1); inf-safe at both ends
    float e = __expf(2.0f * x);
    float r = __builtin_amdgcn_rcpf(e + 1.0f);
    return fmaf(-2.0f, r, 1.0f);
}
__device__ __forceinline__ float fast_sigmoid(float x) {
    float e = __expf(-x);
    return __builtin_amdgcn_rcpf(e + 1.0f);
}

// One wave = one trajectory. 64 lanes = output columns (u-side lanes 0-31, r-side 32-63).
// Weights in registers; activations broadcast through per-wave LDS; no __syncthreads.
__global__ __launch_bounds__(256) void rnn_fused(
    const float* __restrict__ data,
    const float* __restrict__ Wu1, const float* __restrict__ bu1,
    const float* __restrict__ Wu2, const float* __restrict__ bu2,
    const float* __restrict__ Wr1, const float* __restrict__ br1,
    const float* __restrict__ Wr2, const float* __restrict__ br2,
    const float* __restrict__ Wn1, const float* __restrict__ bn1,
    const float* __restrict__ Wn2, const float* __restrict__ bn2,
    float* __restrict__ out_yi, float* __restrict__ out_lat)
{
    __shared__ __align__(16) float YC[4][CAT];   // [y(32) | x(16)]
    __shared__ __align__(16) float CCb[4][CAT];  // [r*y(32) | x(16)]
    __shared__ __align__(16) float H1[4][64];    // layer-1 hidden for u (0..31) and r (32..63)
    __shared__ __align__(16) float HN[4][32];    // layer-1 hidden for n

    const int tid  = threadIdx.x;
    const int w    = tid >> 6;
    const int lane = tid & 63;
    const int c    = lane & 31;   // output column
    const int g    = lane >> 5;   // 0 = u-side, 1 = r-side (also K-split half for n-gate)
    const int b    = (blockIdx.x << 2) + w;

    float* yc = YC[w];
    float* cc = CCb[w];
    float* h1 = H1[w];
    float* hn = HN[w];

    // ---- stage weights into registers (one-time, L2/L3-cached broadcast) ----
    float wa[CAT], wb[HID], wc[24], wd[12];
    float ba, bb, bc, bd;
    {
        const float* W1 = g ? Wr1 : Wu1;
        const float* B1 = g ? br1 : bu1;
        const float* W2 = g ? Wr2 : Wu2;
        const float* B2 = g ? br2 : bu2;
        const bool real = (c < HID);
        #pragma unroll
        for (int k = 0; k < CAT; ++k) {
            int idx = real ? (k * HID + c) : 0;       // clamp: no OOB on padded lanes
            wa[k] = real ? W1[idx] : 0.0f;
        }
        ba = real ? B1[c] : 0.0f;
        #pragma unroll
        for (int k = 0; k < HID; ++k) wb[k] = W2[k * LAT + c];
        bb = B2[c];
        #pragma unroll
        for (int k = 0; k < 24; ++k) {
            int idx = real ? ((g * 24 + k) * HID + c) : 0;
            wc[k] = real ? Wn1[idx] : 0.0f;
        }
        bc = (real && g == 0) ? bn1[c] : 0.0f;
        #pragma unroll
        for (int k = 0; k < 12; ++k) {
            int row = g * 12 + k;
            int idx = (row < HID) ? (row * LAT + c) : 0;
            wd[k] = (row < HID) ? Wn2[idx] : 0.0f;
        }
        bd = (g == 0) ? bn2[c] : 0.0f;
    }

    // ---- x prefetch pipeline (2 steps deep, rotating registers) ----
    const size_t xbase = (size_t)b * T_STEPS * INPD + (lane & 15);
    float xc = data[xbase];                 // t = 0
    float xn = data[xbase + INPD];          // t = 1

    float y_reg = 0.0f;   // lane c owns y[c] (valid on lanes 0-31)
    float u_reg = 0.0f;

    for (int t = 0; t < T_STEPS; ++t) {
        // publish y and x into LDS
        if (lane < 32) {
            yc[c] = y_reg;
            if (lane < 16) { yc[32 + lane] = xc; cc[32 + lane] = xc; }
        }
        // issue prefetch for t+2 (latency hidden under this step)
        int tf = t + 2; tf = (tf < T_STEPS) ? tf : (T_STEPS - 1);
        float xf = data[xbase + (size_t)tf * INPD];

        asm volatile("s_waitcnt lgkmcnt(0)" ::: "memory");

        // ---- Phase A: layer-1 of u,r  (K=48, all 64 lanes) ----
        float a0 = ba, a1 = 0.0f;
        #pragma unroll
        for (int kk = 0; kk < 12; ++kk) {
            float4 v = *(const float4*)(yc + kk * 4);
            a0 = fmaf(v.x, wa[kk*4+0], a0);
            a1 = fmaf(v.y, wa[kk*4+1], a1);
            a0 = fmaf(v.z, wa[kk*4+2], a0);
            a1 = fmaf(v.w, wa[kk*4+3], a1);
        }
        h1[lane] = fast_tanh(a0 + a1);
        asm volatile("s_waitcnt lgkmcnt(0)" ::: "memory");

        // ---- Phase B: layer-2 of u,r  (K=20, all 64 lanes) ----
        a0 = bb; a1 = 0.0f;
        const float* hsrc = h1 + g * 32;
        #pragma unroll
        for (int kk = 0; kk < 5; ++kk) {
            float4 v = *(const float4*)(hsrc + kk * 4);
            a0 = fmaf(v.x, wb[kk*4+0], a0);
            a1 = fmaf(v.y, wb[kk*4+1], a1);
            a0 = fmaf(v.z, wb[kk*4+2], a0);
            a1 = fmaf(v.w, wb[kk*4+3], a1);
        }
        float gate = fast_sigmoid(a0 + a1);
        if (lane < 32) u_reg = gate;                 // u on lanes 0-31
        float y_other = __shfl_xor(y_reg, 32);       // bring y[c] to r-side lanes
        if (lane >= 32) cc[c] = gate * y_other;      // r*y
        asm volatile("s_waitcnt lgkmcnt(0)" ::: "memory");

        // ---- Phase C: layer-1 of n  (K=48 split 24/24 across half-waves) ----
        a0 = bc; a1 = 0.0f;
        #pragma unroll
        for (int kk = 0; kk < 6; ++kk) {
            float4 v = *(const float4*)(cc + g * 24 + kk * 4);
            a0 = fmaf(v.x, wc[kk*4+0], a0);
            a1 = fmaf(v.y, wc[kk*4+1], a1);
            a0 = fmaf(v.z, wc[kk*4+2], a0);
            a1 = fmaf(v.w, wc[kk*4+3], a1);
        }
        float cpart = a0 + a1;
        float csum = cpart + __shfl_xor(cpart, 32);
        if (lane < 32) hn[c] = fast_tanh(csum);
        asm volatile("s_waitcnt lgkmcnt(0)" ::: "memory");

        // ---- Phase D: layer-2 of n (K=20→24 split 12/12) + combine ----
        a0 = bd; a1 = 0.0f;
        #pragma unroll
        for (int kk = 0; kk < 3; ++kk) {
            float4 v = *(const float4*)(hn + g * 12 + kk * 4);
            a0 = fmaf(v.x, wd[kk*4+0], a0);
            a1 = fmaf(v.y, wd[kk*4+1], a1);
            a0 = fmaf(v.z, wd[kk*4+2], a0);
            a1 = fmaf(v.w, wd[kk*4+3], a1);
        }
        float npart = a0 + a1;
        float nsum = npart + __shfl_xor(npart, 32);
        float n = fast_tanh(nsum);
        if (lane < 32) {
            float ny = fmaf(u_reg, y_reg - n, n);    // (1-u)*n + u*y
            out_lat[((size_t)b * T_STEPS + t) * LAT + c] = ny;
            y_reg = ny;
        }
        // rotate x pipeline
        xc = xn; xn = xf;
    }

    if (lane < 32) out_yi[(size_t)b * LAT + c] = y_reg;
}

extern "C" void kernel_launch(void* const* d_in, const int* in_sizes, int n_in,
                              void* d_out, int out_size, void* d_ws, size_t ws_size,
                              hipStream_t stream) {
    const float* data = (const float*)d_in[0];
    // d_in[1] = time_steps (unused by reference math)
    const float* Wu1 = (const float*)d_in[2];
    const float* bu1 = (const float*)d_in[3];
    const float* Wu2 = (const float*)d_in[4];
    const float* bu2 = (const float*)d_in[5];
    const float* Wr1 = (const float*)d_in[6];
    const float* br1 = (const float*)d_in[7];
    const float* Wr2 = (const float*)d_in[8];
    const float* br2 = (const float*)d_in[9];
    const float* Wn1 = (const float*)d_in[10];
    const float* bn1 = (const float*)d_in[11];
    const float* Wn2 = (const float*)d_in[12];
    const float* bn2 = (const float*)d_in[13];

    float* out_yi  = (float*)d_out;
    float* out_lat = out_yi + (size_t)NTRAJ * LAT;

    rnn_fused<<<NTRAJ / 4, 256, 0, stream>>>(
        data, Wu1, bu1, Wu2, bu2, Wr1, br1, Wr2, br2, Wn1, bn1, Wn2, bn2,
        out_yi, out_lat);
}